// Round 1
// 521.374 us; speedup vs baseline: 1.0228x; 1.0228x over previous
//
#include <hip/hip_runtime.h>
#include <stdint.h>
#include <stddef.h>

#define CH     512
#define TT     32
#define NBLK   32
#define NBATCH 32
#define NCHUNK 8      // WGs per batch (64 channels each)
#define NTHR   1024   // 16 waves, 4 per SIMD

// ---- transpose: WT[j][c] = W[c][j] (row j = presyn channel, 2 KiB/row) ----
__global__ __launch_bounds__(256) void transpose_k(const float* __restrict__ W,
                                                   float* __restrict__ WT) {
    __shared__ float tile[64][65];
    const int bx = blockIdx.x & 7, by = blockIdx.x >> 3;
    const int lx = threadIdx.x & 63, ly = threadIdx.x >> 6;
    for (int r = ly; r < 64; r += 4)
        tile[r][lx] = W[(size_t)(by * 64 + r) * CH + bx * 64 + lx];
    __syncthreads();
    for (int r = ly; r < 64; r += 4)
        WT[(size_t)(bx * 64 + r) * CH + by * 64 + lx] = tile[lx][r];
}

// published word: two 16b entries [tag4 | t6 | ch6]; t=63 = no spike
// ent8 entry: (ch_global << 5) | t  -> row byte offset = (e & 0xFFE0) << 6
__global__ __launch_bounds__(NTHR, 4) void snn_kernel(
    const float* __restrict__ x,
    const float* __restrict__ beta_raw,
    const float* __restrict__ WT,
    const float* __restrict__ p_raw,
    const float* __restrict__ b_raw,
    int*       __restrict__ ent_g,     // [NBATCH][256] packed tagged words
    float*     __restrict__ out)
{
    __shared__ float rec8[8][2112];    // [gather-wave][l*33+t]; rec8[0] x-seeded
    __shared__ float rec_tot[2112];
    __shared__ int   ent8[8][512];     // PRIVATE per-gather-wave compacted spike list
    __shared__ int   tf_lds[64];
    __shared__ int   tmp16[64];        // producer sort scratch

    const int bidx = blockIdx.x;
    const int b    = bidx & (NBATCH - 1);   // batch's 8 WGs share an XCD
    const int kown = bidx >> 5;             // channel chunk 0..7
    const int tid  = threadIdx.x;
    const int l    = tid & 63;
    const int g    = tid >> 6;              // wave 0..15
    const size_t base = ((size_t)b) << 19;  // b*CH*1024 floats
    int* pg = ent_g + (b << 8);

    const int c = (kown << 6) + l;          // wave0-lane channel
    const float beta  = fminf(fmaxf(beta_raw[c], 0.001f), 0.999f);
    const float p     = fminf(fabsf(p_raw[c]), 0.999f);
    const float bb    = fminf(fmaxf(fabsf(b_raw[c]), 0.001f), 1.0f);
    const float inv_p = 1.0f / p;
    float p32; { float t2 = p*p, t4 = t2*t2, t8 = t4*t4, t16 = t8*t8; p32 = t16*t16; }
    float a_mult = 0.f, v_init = 0.f;
    int   zero_start = 0;
    const unsigned long long lowmask = (1ull << l) - 1ull;

    // ---- pre-loop: seed rec8[0] with x block 0; zero rec8[1..7] ----
    if (tid < 512) {
        const int ch = tid >> 3, q = tid & 7;
        const float4 v = *(const float4*)(x + base + ((size_t)((kown << 6) + ch) << 10) + (q << 2));
        float* d = &rec8[0][ch * 33 + (q << 2)];
        d[0] = v.x; d[1] = v.y; d[2] = v.z; d[3] = v.w;
    } else {
        const int t0 = tid - 512;
        #pragma unroll
        for (int z = 0; z < 29; ++z) {
            const int k = t0 + (z << 9);
            if (k < 14784) (&rec8[1][0])[k] = 0.f;
        }
    }
    __syncthreads();

    for (int n = 0; n < NBLK; ++n) {
        // ---- C: waves 0-7 self-poll + scatter(private) + gather
        //         waves 8-15: x(n+1) prefetch + out(n-1) store (1 float4 each) ----
        float4 xstage;
        if (g >= 8) {
            const int slot = tid - 512;
            const int ch = slot >> 3, q = slot & 7;
            if (n + 1 < NBLK)
                xstage = *(const float4*)(x + base + ((size_t)((kown << 6) + ch) << 10) + ((n + 1) << 5) + (q << 2));
            if (n > 0) {
                const int tf = tf_lds[ch];
                const int t0 = q << 2;
                float4 v;
                v.x = (t0     == tf) ? 1.f : 0.f;
                v.y = (t0 + 1 == tf) ? 1.f : 0.f;
                v.z = (t0 + 2 == tf) ? 1.f : 0.f;
                v.w = (t0 + 3 == tf) ? 1.f : 0.f;
                *(float4*)(out + base + ((size_t)((kown << 6) + ch) << 10) + ((n - 1) << 5) + t0) = v;
            }
        } else if (n > 0) {
            // ---- per-wave poll: lane l owns words {l, 64+l, 128+l, 192+l}
            //      (word w: chunk = w>>5, in-chunk word j = w&31)
            //      per-word LATCH on tag match (a matched word is captured and
            //      never re-read -> robust against the producer moving to tag n)
            const unsigned want = (unsigned)((n - 1) & 15);
            unsigned w0 = 0, w1 = 0, w2 = 0, w3 = 0;
            {
                bool d0 = false, d1 = false, d2 = false, d3 = false;
                while (true) {
#define TAGOK(v) (((((v) >> 12) & 15u) == want) && ((((v) >> 28) & 15u) == want))
                    if (!d0) { const unsigned v = (unsigned)__hip_atomic_load(pg + l,       __ATOMIC_RELAXED, __HIP_MEMORY_SCOPE_AGENT); if (TAGOK(v)) { w0 = v; d0 = true; } }
                    if (!d1) { const unsigned v = (unsigned)__hip_atomic_load(pg + 64 + l,  __ATOMIC_RELAXED, __HIP_MEMORY_SCOPE_AGENT); if (TAGOK(v)) { w1 = v; d1 = true; } }
                    if (!d2) { const unsigned v = (unsigned)__hip_atomic_load(pg + 128 + l, __ATOMIC_RELAXED, __HIP_MEMORY_SCOPE_AGENT); if (TAGOK(v)) { w2 = v; d2 = true; } }
                    if (!d3) { const unsigned v = (unsigned)__hip_atomic_load(pg + 192 + l, __ATOMIC_RELAXED, __HIP_MEMORY_SCOPE_AGENT); if (TAGOK(v)) { w3 = v; d3 = true; } }
#undef TAGOK
                    if (d0 && d1 && d2 && d3) break;
                    __builtin_amdgcn_s_sleep(1);
                }
            }
            // ---- decode + per-chunk counts via in-wave ballots (no cnt_lds, no barrier)
            const unsigned long long LO32 = 0xFFFFFFFFull;
            const int e00 = (int)(w0 & 0xFFFFu), e01 = (int)((w0 >> 16) & 0xFFFFu);
            const int e10 = (int)(w1 & 0xFFFFu), e11 = (int)((w1 >> 16) & 0xFFFFu);
            const int e20 = (int)(w2 & 0xFFFFu), e21 = (int)((w2 >> 16) & 0xFFFFu);
            const int e30 = (int)(w3 & 0xFFFFu), e31 = (int)((w3 >> 16) & 0xFFFFu);
            const int s00 = ((e00 >> 6) & 63) != 63, s01 = ((e01 >> 6) & 63) != 63;
            const int s10 = ((e10 >> 6) & 63) != 63, s11 = ((e11 >> 6) & 63) != 63;
            const int s20 = ((e20 >> 6) & 63) != 63, s21 = ((e21 >> 6) & 63) != 63;
            const int s30 = ((e30 >> 6) & 63) != 63, s31 = ((e31 >> 6) & 63) != 63;
            const unsigned long long b00 = __ballot(s00 != 0), b01 = __ballot(s01 != 0);
            const unsigned long long b10 = __ballot(s10 != 0), b11 = __ballot(s11 != 0);
            const unsigned long long b20 = __ballot(s20 != 0), b21 = __ballot(s21 != 0);
            const unsigned long long b30 = __ballot(s30 != 0), b31 = __ballot(s31 != 0);
            const int cnt0 = (int)__popcll(b00 & LO32) + (int)__popcll(b01 & LO32);
            const int cnt1 = (int)__popcll(b00 >> 32)  + (int)__popcll(b01 >> 32);
            const int cnt2 = (int)__popcll(b10 & LO32) + (int)__popcll(b11 & LO32);
            const int cnt3 = (int)__popcll(b10 >> 32)  + (int)__popcll(b11 >> 32);
            const int cnt4 = (int)__popcll(b20 & LO32) + (int)__popcll(b21 & LO32);
            const int cnt5 = (int)__popcll(b20 >> 32)  + (int)__popcll(b21 >> 32);
            const int cnt6 = (int)__popcll(b30 & LO32) + (int)__popcll(b31 & LO32);
            const int cnt7 = (int)__popcll(b30 >> 32)  + (int)__popcll(b31 >> 32);
            const int pf1 = cnt0;
            const int pf2 = pf1 + cnt1;
            const int pf3 = pf2 + cnt2;
            const int pf4 = pf3 + cnt3;
            const int pf5 = pf4 + cnt4;
            const int pf6 = pf5 + cnt5;
            const int pf7 = pf6 + cnt6;
            const int L   = pf7 + cnt7;
            // ---- scatter into this wave's private list (spikes-first within chunk
            //      is guaranteed by the producer's sort, so word j -> positions 2j,2j+1)
            const int hi = (l >> 5) & 1;
            const int j2 = (l & 31) << 1;
            int* entW = &ent8[g][0];
            {
                const int pc_ = hi ? pf1 : 0;    const int cb = (0 + hi) << 6;
                if (s00) entW[pc_ + j2]     = ((cb | (e00 & 63)) << 5) | ((e00 >> 6) & 31);
                if (s01) entW[pc_ + j2 + 1] = ((cb | (e01 & 63)) << 5) | ((e01 >> 6) & 31);
            }
            {
                const int pc_ = hi ? pf3 : pf2;  const int cb = (2 + hi) << 6;
                if (s10) entW[pc_ + j2]     = ((cb | (e10 & 63)) << 5) | ((e10 >> 6) & 31);
                if (s11) entW[pc_ + j2 + 1] = ((cb | (e11 & 63)) << 5) | ((e11 >> 6) & 31);
            }
            {
                const int pc_ = hi ? pf5 : pf4;  const int cb = (4 + hi) << 6;
                if (s20) entW[pc_ + j2]     = ((cb | (e20 & 63)) << 5) | ((e20 >> 6) & 31);
                if (s21) entW[pc_ + j2 + 1] = ((cb | (e21 & 63)) << 5) | ((e21 >> 6) & 31);
            }
            {
                const int pc_ = hi ? pf7 : pf6;  const int cb = (6 + hi) << 6;
                if (s30) entW[pc_ + j2]     = ((cb | (e30 & 63)) << 5) | ((e30 >> 6) & 31);
                if (s31) entW[pc_ + j2 + 1] = ((cb | (e31 & 63)) << 5) | ((e31 >> 6) & 31);
            }
            __threadfence_block();   // drain ds_writes before same-wave cross-lane ds_read
            // ---- gather (identical entry->wave assignment & summation order as before)
            if (L > 0) {
                const char* WTb = (const char*)WT;
                const int col4 = ((kown << 6) + l) << 2;
                float* myrec = &rec8[g][l * 33];
                float acc = 0.f; int cur_t = -1;
                #pragma unroll
                for (int s = 0; s < 8; ++s) {
                    const int segbase = s << 6;
                    if (segbase < L) {
                        const int ve = entW[segbase + l];
                        int S[8]; float F[8];
                        #pragma unroll
                        for (int k = 0; k < 8; ++k) {
                            const int idx = segbase + g + (k << 3);
                            int sv = __builtin_amdgcn_readlane(ve, g + (k << 3));
                            const int ok = idx < L;
                            S[k] = ok ? sv : -1;
                            sv = ok ? sv : 0;
                            F[k] = *(const float*)(WTb + ((sv & 0xFFE0) << 6) + col4);
                        }
                        #pragma unroll
                        for (int k = 0; k < 8; ++k) {
                            if (S[k] >= 0) {
                                const int t = S[k] & 31;
                                if (t != cur_t) { if (cur_t >= 0) myrec[cur_t] += acc; acc = 0.f; cur_t = t; }
                                acc += F[k];
                            }
                        }
                    }
                }
                if (cur_t >= 0) myrec[cur_t] += acc;
            }
        }
        __syncthreads();   // B3: partials complete

        // ---- D: reduce 8 partials (x seeded in rec8[0]); all 1024 threads ----
        #pragma unroll
        for (int r = 0; r < 2; ++r) {
            const int e = tid + (r << 10);
            const int idx = ((e >> 5) * 33) + (e & 31);
            rec_tot[idx] = ((rec8[0][idx] + rec8[1][idx]) + (rec8[2][idx] + rec8[3][idx]))
                         + ((rec8[4][idx] + rec8[5][idx]) + (rec8[6][idx] + rec8[7][idx]));
        }
        __syncthreads();   // B4: rec_tot ready

        // ---- E: dynamics+publish (wave 0, prio 1, fused spike-rank)
        //         | x-seed write (waves 8-15) | zero (waves 1-7) ----
        if (g == 0) {
            __builtin_amdgcn_s_setprio(1);
            float mem = 0.f, pc = p, pca = p;
            int t_first = -1, mypos = 0;
            unsigned prefc = 0;
            #pragma unroll
            for (int t = 0; t < TT; ++t) {
                const float rv = rec_tot[l * 33 + t];
                float cur = (t >= zero_start) ? rv : 0.f;
                if (t == 0) cur += beta * v_init;
                mem = beta * mem + cur;
                const float vth = 1.f + bb * pc * a_mult;
                const bool fire = (mem - vth > 0.f) && (t_first < 0);
                const unsigned long long bal = __ballot(fire);
                if (fire) {
                    t_first = t; pca = pc;
                    mypos = (int)prefc + (int)__popcll(bal & lowmask);
                }
                prefc += (unsigned)__popcll(bal);
                pc *= p;
            }
            if (t_first >= 0) {
                float pd = 1.f;
                for (int m = 31 - t_first; m > 0; --m) pd *= p;
                a_mult = (pca * a_mult + inv_p) * pd;
                v_init = 0.f; zero_start = t_first;
            } else {
                a_mult = p32 * a_mult;
                v_init = mem; zero_start = 0;
            }
            tf_lds[l] = t_first;
            if (n + 1 < NBLK) {
                const bool sp = (t_first >= 0);
                const unsigned long long balS = __ballot(sp);
                const int cntS = (int)prefc;
                if (!sp) mypos = cntS + (int)__popcll(~balS & lowmask);
                const int tval = sp ? t_first : 63;
                tmp16[mypos] = ((n & 15) << 12) | (tval << 6) | l;
                __threadfence_block();   // drain ds_write before cross-lane ds_read
                if (l < 32) {
                    const int wlo = tmp16[l << 1];
                    const int whi = tmp16[(l << 1) | 1];
                    __hip_atomic_store(pg + (kown << 5) + l, wlo | (whi << 16),
                                       __ATOMIC_RELAXED, __HIP_MEMORY_SCOPE_AGENT);
                }
            }
            __builtin_amdgcn_s_setprio(0);
        } else if (g >= 8) {
            if (n + 1 < NBLK) {
                const int slot = tid - 512;
                const int ch = slot >> 3, q = slot & 7;
                float* d = &rec8[0][ch * 33 + (q << 2)];
                d[0] = xstage.x; d[1] = xstage.y; d[2] = xstage.z; d[3] = xstage.w;
            }
        } else {
            if (n + 1 < NBLK) {
                const int t0 = tid - 64;
                #pragma unroll
                for (int z = 0; z < 33; ++z)
                    (&rec8[1][0])[t0 + 448 * z] = 0.f;
            }
        }
        __syncthreads();   // B5
    }

    // ---- final out block 31 ----
    if (tid < 512) {
        const int ch = tid >> 3, q = tid & 7;
        const int tf = tf_lds[ch];
        const int t0 = q << 2;
        float4 v;
        v.x = (t0     == tf) ? 1.f : 0.f;
        v.y = (t0 + 1 == tf) ? 1.f : 0.f;
        v.z = (t0 + 2 == tf) ? 1.f : 0.f;
        v.w = (t0 + 3 == tf) ? 1.f : 0.f;
        *(float4*)(out + base + ((size_t)((kown << 6) + ch) << 10) + (31 << 5) + t0) = v;
    }
}

extern "C" void kernel_launch(void* const* d_in, const int* in_sizes, int n_in,
                              void* d_out, int out_size, void* d_ws, size_t ws_size,
                              hipStream_t stream) {
    (void)in_sizes; (void)n_in; (void)out_size;
    const float* x   = (const float*)d_in[0];
    const float* br  = (const float*)d_in[1];
    const float* W   = (const float*)d_in[2];
    const float* pr  = (const float*)d_in[3];
    const float* bbr = (const float*)d_in[4];
    float* out = (float*)d_out;

    const size_t wt_bytes  = (size_t)CH * CH * sizeof(float);     // 1 MiB
    const size_t ent_bytes = (size_t)NBATCH * 256 * sizeof(int);  // 32 KiB
    if (ws_size < wt_bytes + ent_bytes) return;

    float* WT    = (float*)d_ws;
    int*   ent_g = (int*)((char*)d_ws + wt_bytes);
    // no memset: 0xAA poison tag (10) never matches first wanted tag (0),
    // and every slot is rewritten each step thereafter

    transpose_k<<<64, 256, 0, stream>>>(W, WT);
    snn_kernel<<<NBATCH * NCHUNK, NTHR, 0, stream>>>(x, br, WT, pr, bbr, ent_g, out);
}